// Round 7
// baseline (230.918 us; speedup 1.0000x reference)
//
#include <hip/hip_runtime.h>

#define BLK 256
#define CPB 128                  // cells per block
#define CH 30
#define TILE_F4 (CPB * CH / 4)   // 960 float4 per tensor = 15 chunks of 64

// async global->LDS, 16B per lane; LDS base is wave-uniform, HW adds lane*16
__device__ __forceinline__ void gld_lds16(const float* g, float* l) {
    __builtin_amdgcn_global_load_lds(
        (const __attribute__((address_space(1))) void*)(const void*)g,
        (__attribute__((address_space(3))) void*)(void*)l,
        16, 0, 0);
}

__device__ __forceinline__ float cell_loss(const float* __restrict__ p,
                                           const float* __restrict__ t) {
    const float conf_t = t[4];

    // target box -> xyxy (exact /14.0f to match numpy argmax decisions)
    const float tw = t[2], th = t[3];
    const float tx = t[0] / 14.0f, ty = t[1] / 14.0f;
    const float tx1 = tx - 0.5f * tw, ty1 = ty - 0.5f * th;
    const float tx2 = tx + 0.5f * tw, ty2 = ty + 0.5f * th;
    const float ta = tw * th;

    float iou0, iou1;
    #pragma unroll
    for (int b = 0; b < 2; ++b) {
        const float* pb = p + b * 5;
        const float pw = pb[2], ph = pb[3];
        const float px = pb[0] / 14.0f, py = pb[1] / 14.0f;
        const float x1 = px - 0.5f * pw, y1 = py - 0.5f * ph;
        const float x2 = px + 0.5f * pw, y2 = py + 0.5f * ph;
        const float w = fmaxf(fminf(x2, tx2) - fmaxf(x1, tx1), 0.0f);
        const float h = fmaxf(fminf(y2, ty2) - fmaxf(y1, ty1), 0.0f);
        const float inter = w * h;
        const float v = inter / (pw * ph + ta - inter);
        if (b == 0) iou0 = v; else iou1 = v;
    }

    const int resp = (iou1 > iou0) ? 1 : 0;      // argmax, first-max ties
    const float max_iou = fmaxf(iou0, iou1);
    const float* br = p + resp * 5;
    const float* bn = p + (1 - resp) * 5;

    const float coo = (conf_t > 0.0f) ? 1.0f : 0.0f;
    const float noo = (conf_t == 0.0f) ? 1.0f : 0.0f;

    const float d0 = br[0] - t[0];
    const float d1 = br[1] - t[1];
    const float d2 = sqrtf(br[2]) - sqrtf(t[2]);
    const float d3 = sqrtf(br[3]) - sqrtf(t[3]);
    const float loc = d0 * d0 + d1 * d1 + d2 * d2 + d3 * d3;

    const float dc = br[4] - max_iou;
    const float contain = dc * dc;
    const float ncontain = bn[4] * bn[4];

    const float n4 = p[4] - t[4];
    const float n9 = p[9] - t[9];
    const float noobj = n4 * n4 + n9 * n9;

    float cls = 0.0f;
    #pragma unroll
    for (int c = 10; c < 30; ++c) {
        const float d = p[c] - t[c];
        cls += d * d;
    }

    return coo * (5.0f * loc + 2.0f * contain + ncontain + cls)
         + 0.5f * noo * noobj;
}

__global__ __launch_bounds__(BLK) void yolo_loss_kernel(
    const float* __restrict__ pred, const float* __restrict__ targ,
    float* __restrict__ out, int nblocks, float inv_n)
{
    // 2 x 128 cells x 120 B = 30720 B LDS -> 5 blocks/CU = 20 waves/CU
    __shared__ __align__(16) float sp[CPB * CH];
    __shared__ __align__(16) float st[CPB * CH];
    const int tid  = threadIdx.x;
    const int wave = tid >> 6;
    const int lane = tid & 63;

    // XCD-bijective swizzle (nblocks % 8 == 0): each XCD streams a
    // contiguous chunk of the input
    const int nx  = nblocks >> 3;
    const int bid = (blockIdx.x & 7) * nx + (blockIdx.x >> 3);

    const size_t base = (size_t)bid * (CPB * CH);
    const float* gp = pred + base;
    const float* gt = targ + base;

    // stage both tensors: 15 chunks of 1KB each, lanes contiguous (16B/lane)
    #pragma unroll
    for (int c = wave; c < 15; c += 4) {
        gld_lds16(gp + c * 256 + lane * 4, sp + c * 256);
        gld_lds16(gt + c * 256 + lane * 4, st + c * 256);
    }
    __syncthreads();   // vmcnt(0) drain + barrier; overlap comes from 5 blocks/CU

    float loss = 0.0f;
    if (tid < CPB)
        loss = cell_loss(sp + tid * CH, st + tid * CH);

    // reduce over the 2 compute waves
    #pragma unroll
    for (int off = 32; off > 0; off >>= 1) loss += __shfl_down(loss, off);

    __shared__ float wsum[2];
    if (tid < CPB && lane == 0) wsum[wave] = loss;
    __syncthreads();
    if (tid == 0) atomicAdd(out, (wsum[0] + wsum[1]) * inv_n);
}

extern "C" void kernel_launch(void* const* d_in, const int* in_sizes, int n_in,
                              void* d_out, int out_size, void* d_ws, size_t ws_size,
                              hipStream_t stream) {
    const float* pred = (const float*)d_in[0];
    const float* targ = (const float*)d_in[1];
    float* out = (float*)d_out;

    const long long total = in_sizes[0];          // 4096*14*14*30
    const int ncells = (int)(total / CH);         // 802816 = 6272 * 128
    const int N = ncells / 196;                   // 4096
    const float inv_n = 1.0f / (float)N;
    const int nblocks = ncells / CPB;             // 6272, divisible by 8

    hipMemsetAsync(out, 0, sizeof(float) * out_size, stream);
    hipLaunchKernelGGL(yolo_loss_kernel, dim3(nblocks), dim3(BLK), 0, stream,
                       pred, targ, out, nblocks, inv_n);
}

// Round 9
// 216.065 us; speedup vs baseline: 1.0687x; 1.0687x over previous
//
#include <hip/hip_runtime.h>

#define BLK 256
#define CH 30

// Branchless per-cell loss; all indices compile-time (register-resident).
__device__ __forceinline__ float cell_loss(const float* __restrict__ p,
                                           const float* __restrict__ t) {
    const float conf_t = t[4];

    const float tw = t[2], th = t[3];
    const float tx = t[0] / 14.0f, ty = t[1] / 14.0f;
    const float tx1 = tx - 0.5f * tw, ty1 = ty - 0.5f * th;
    const float tx2 = tx + 0.5f * tw, ty2 = ty + 0.5f * th;
    const float ta = tw * th;

    const float b0x = p[0], b0y = p[1], b0w = p[2], b0h = p[3], b0c = p[4];
    const float b1x = p[5], b1y = p[6], b1w = p[7], b1h = p[8], b1c = p[9];

    float iou0, iou1;
    {
        const float px = b0x / 14.0f, py = b0y / 14.0f;
        const float x1 = px - 0.5f * b0w, y1 = py - 0.5f * b0h;
        const float x2 = px + 0.5f * b0w, y2 = py + 0.5f * b0h;
        const float w = fmaxf(fminf(x2, tx2) - fmaxf(x1, tx1), 0.0f);
        const float h = fmaxf(fminf(y2, ty2) - fmaxf(y1, ty1), 0.0f);
        const float inter = w * h;
        iou0 = inter / (b0w * b0h + ta - inter);
    }
    {
        const float px = b1x / 14.0f, py = b1y / 14.0f;
        const float x1 = px - 0.5f * b1w, y1 = py - 0.5f * b1h;
        const float x2 = px + 0.5f * b1w, y2 = py + 0.5f * b1h;
        const float w = fmaxf(fminf(x2, tx2) - fmaxf(x1, tx1), 0.0f);
        const float h = fmaxf(fminf(y2, ty2) - fmaxf(y1, ty1), 0.0f);
        const float inter = w * h;
        iou1 = inter / (b1w * b1h + ta - inter);
    }

    const bool r1 = iou1 > iou0;              // argmax, first-max on ties
    const float max_iou = fmaxf(iou0, iou1);
    const float brx = r1 ? b1x : b0x;
    const float bry = r1 ? b1y : b0y;
    const float brw = r1 ? b1w : b0w;
    const float brh = r1 ? b1h : b0h;
    const float brc = r1 ? b1c : b0c;
    const float bnc = r1 ? b0c : b1c;

    const float coo = (conf_t > 0.0f) ? 1.0f : 0.0f;
    const float noo = (conf_t == 0.0f) ? 1.0f : 0.0f;

    const float d0 = brx - t[0];
    const float d1 = bry - t[1];
    const float d2 = sqrtf(brw) - sqrtf(t[2]);
    const float d3 = sqrtf(brh) - sqrtf(t[3]);
    const float loc = d0 * d0 + d1 * d1 + d2 * d2 + d3 * d3;

    const float dc = brc - max_iou;
    const float contain = dc * dc;
    const float ncontain = bnc * bnc;

    const float n4 = p[4] - t[4];
    const float n9 = p[9] - t[9];
    const float noobj = n4 * n4 + n9 * n9;

    float cls = 0.0f;
    #pragma unroll
    for (int c = 10; c < 30; ++c) {
        const float d = p[c] - t[c];
        cls += d * d;
    }

    return coo * (5.0f * loc + 2.0f * contain + ncontain + cls)
         + 0.5f * noo * noobj;
}

__global__ __launch_bounds__(BLK, 3) void yolo_pass1(
    const float* __restrict__ pred, const float* __restrict__ targ,
    float* __restrict__ ws, int npairs)
{
    const int pr = blockIdx.x * BLK + threadIdx.x;
    float loss = 0.0f;
    if (pr < npairs) {
        // pair of cells = 240 B = 15 aligned float4s per tensor
        const float4* gp = (const float4*)pred + (size_t)pr * 15;
        const float4* gt = (const float4*)targ + (size_t)pr * 15;
        float4 pv[15], tv[15];
        #pragma unroll
        for (int k = 0; k < 15; ++k) pv[k] = gp[k];
        #pragma unroll
        for (int k = 0; k < 15; ++k) tv[k] = gt[k];
        // Force all 30 loads to complete before any consumption: pins full
        // 480 B/lane in flight (MLP), prevents the compiler sinking loads
        // into consumer-order batches (R5 showed VGPR=64 => batches of ~4).
        // NOTE: scalar components only — "v" can't bind a 128-bit vector.
        #pragma unroll
        for (int k = 0; k < 15; ++k) {
            asm volatile("" :: "v"(pv[k].x), "v"(pv[k].y),
                               "v"(pv[k].z), "v"(pv[k].w));
            asm volatile("" :: "v"(tv[k].x), "v"(tv[k].y),
                               "v"(tv[k].z), "v"(tv[k].w));
        }
        const float* p = (const float*)pv;
        const float* t = (const float*)tv;
        loss = cell_loss(p, t) + cell_loss(p + CH, t + CH);
    }

    // wave shuffle-reduce, then block combine; ONE plain store per block
    #pragma unroll
    for (int off = 32; off > 0; off >>= 1) loss += __shfl_down(loss, off);

    __shared__ float wsum[BLK / 64];
    const int wid = threadIdx.x >> 6;
    const int lane = threadIdx.x & 63;
    if (lane == 0) wsum[wid] = loss;
    __syncthreads();
    if (threadIdx.x == 0) {
        float s = 0.0f;
        #pragma unroll
        for (int w = 0; w < BLK / 64; ++w) s += wsum[w];
        ws[blockIdx.x] = s;              // no atomics anywhere
    }
}

__global__ __launch_bounds__(BLK) void yolo_pass2(
    const float* __restrict__ ws, float* __restrict__ out,
    int nparts, float inv_n)
{
    float s = 0.0f;
    for (int i = threadIdx.x; i < nparts; i += BLK) s += ws[i];
    #pragma unroll
    for (int off = 32; off > 0; off >>= 1) s += __shfl_down(s, off);

    __shared__ float wsum[BLK / 64];
    const int wid = threadIdx.x >> 6;
    const int lane = threadIdx.x & 63;
    if (lane == 0) wsum[wid] = s;
    __syncthreads();
    if (threadIdx.x == 0) {
        float tot = 0.0f;
        #pragma unroll
        for (int w = 0; w < BLK / 64; ++w) tot += wsum[w];
        out[0] = tot * inv_n;            // overwrites poison; no memset needed
    }
}

extern "C" void kernel_launch(void* const* d_in, const int* in_sizes, int n_in,
                              void* d_out, int out_size, void* d_ws, size_t ws_size,
                              hipStream_t stream) {
    const float* pred = (const float*)d_in[0];
    const float* targ = (const float*)d_in[1];
    float* out = (float*)d_out;
    float* ws  = (float*)d_ws;

    const long long total = in_sizes[0];          // 4096*14*14*30
    const int ncells = (int)(total / CH);         // 802816
    const int N = ncells / 196;                   // 4096
    const float inv_n = 1.0f / (float)N;
    const int npairs = ncells / 2;                // 401408 = 1568 * 256

    const int grid = (npairs + BLK - 1) / BLK;    // 1568
    hipLaunchKernelGGL(yolo_pass1, dim3(grid), dim3(BLK), 0, stream,
                       pred, targ, ws, npairs);
    hipLaunchKernelGGL(yolo_pass2, dim3(1), dim3(BLK), 0, stream,
                       ws, out, grid, inv_n);
}